// Round 7
// baseline (396.817 us; speedup 1.0000x reference)
//
#include <hip/hip_runtime.h>
#include <hip/hip_bf16.h>
#include <stdint.h>

// TernaryLinear: out = scale * (x_bf16 @ wq_bf16^T), scale = mean|W|+1e-8
// M=8192, K=2048, N=8192. fp32 in/out.
//
// GEMM: 256x256 tile, BK=64, 8 waves (2x4). R5 base + single-set read lookahead.
// Quadrant order Q0(a03,b01) Q1(a03,b23) Q3(a47,b23) Q2(a47,b01); reads 4/8/8/4:
//   ph1: RD_B01(CB) [0-ahead]      | MFMA Q0
//   ph2: RD_A47(CB) [1-ahead]      | MFMA Q1 | vm(0)+BAR   <- youngest load is 2
//        phases old (~1240cyc >= 900 HBM worst case): drain ~free; forces T+1.
//   ph3: RD_A03(OB) [2-ahead] | stage B(T+2)->CB.B | MFMA Q3 | BAR
//   ph4: RD_B23(OB) [2-ahead] | stage A(T+2)->CB.A | MFMA Q2
// Liveness (single sets): b01 reload ph1, last use Q2@ph4 prev tile; a47 reload
// ph2, last use Q2@ph4 prev; a03 reload ph3, last use Q1@ph2; b23 reload ph4,
// last use Q3@ph3. WAR: CB.B readers (b01@ph1 consumed ph1; b23 consumed
// Q1@ph2) retire < ph2-end BAR -> B-stage@ph3 safe. CB.A readers (a03 consumed
// ph1/ph2; a47 consumed Q3@ph3) retire < ph3-end BAR -> A-stage@ph4 safe.
// RAW: vm(0)@ph2-end + BAR makes A(T+1),B(T+1) (staged T-1 ph4/ph3) visible
// chip-wide before any ph3/ph4 read of OB.

typedef __attribute__((ext_vector_type(8))) short   s16x8;
typedef __attribute__((ext_vector_type(4))) float   f32x4;

#define K_DIM   2048
#define K2      4096        // row stride bytes (bf16)
#define N_DIM   8192
#define N4      4194304     // 8192*2048/4

// ---------------- scale reduction ----------------
__global__ void k_abs_part(const float4* __restrict__ w4, float* __restrict__ part) {
    int tid = blockIdx.x * 256 + threadIdx.x;
    float s = 0.f;
    for (int i = tid; i < N4; i += gridDim.x * 256) {
        float4 v = w4[i];
        s += fabsf(v.x) + fabsf(v.y) + fabsf(v.z) + fabsf(v.w);
    }
    for (int off = 32; off > 0; off >>= 1) s += __shfl_down(s, off, 64);
    __shared__ float tmp[4];
    int lane = threadIdx.x & 63, wid = threadIdx.x >> 6;
    if (lane == 0) tmp[wid] = s;
    __syncthreads();
    if (threadIdx.x == 0) part[blockIdx.x] = tmp[0] + tmp[1] + tmp[2] + tmp[3];
}

__global__ void k_abs_final(const float* __restrict__ part, float* __restrict__ scale) {
    float s = part[threadIdx.x] + part[threadIdx.x + 256] +
              part[threadIdx.x + 512] + part[threadIdx.x + 768];
    for (int off = 32; off > 0; off >>= 1) s += __shfl_down(s, off, 64);
    __shared__ float tmp[4];
    int lane = threadIdx.x & 63, wid = threadIdx.x >> 6;
    if (lane == 0) tmp[wid] = s;
    __syncthreads();
    if (threadIdx.x == 0) scale[0] = (tmp[0] + tmp[1] + tmp[2] + tmp[3]) / 16777216.0f + 1e-8f;
}

// ---------------- fused W-quant + X-convert ----------------
__device__ __forceinline__ uint32_t f2b(float f) {
    uint32_t u = __builtin_bit_cast(uint32_t, f);
    return (u + 0x7FFFu + ((u >> 16) & 1u)) >> 16;  // RNE
}

__global__ void k_prep(const float4* __restrict__ w4, const float4* __restrict__ x4,
                       const float* __restrict__ scale_p,
                       uint2* __restrict__ wq, uint2* __restrict__ xb) {
    int tid = (blockIdx.x & 2047) * 256 + threadIdx.x;
    if (blockIdx.x < 2048) {
        const float sc = *scale_p;
        for (int i = tid; i < N4; i += 2048 * 256) {
            float4 v = w4[i];
            float q0 = rintf(v.x / sc), q1 = rintf(v.y / sc);
            float q2 = rintf(v.z / sc), q3 = rintf(v.w / sc);
            uint32_t b0 = (q0 == 0.f) ? 0u : (q0 > 0.f ? 0x3F80u : 0xBF80u);
            uint32_t b1 = (q1 == 0.f) ? 0u : (q1 > 0.f ? 0x3F80u : 0xBF80u);
            uint32_t b2 = (q2 == 0.f) ? 0u : (q2 > 0.f ? 0x3F80u : 0xBF80u);
            uint32_t b3 = (q3 == 0.f) ? 0u : (q3 > 0.f ? 0x3F80u : 0xBF80u);
            uint2 o; o.x = b0 | (b1 << 16); o.y = b2 | (b3 << 16);
            wq[i] = o;
        }
    } else {
        for (int i = tid; i < N4; i += 2048 * 256) {
            float4 v = x4[i];
            uint2 o;
            o.x = f2b(v.x) | (f2b(v.y) << 16);
            o.y = f2b(v.z) | (f2b(v.w) << 16);
            xb[i] = o;
        }
    }
}

// ---------------- GEMM ----------------
__device__ __forceinline__ void mfma16(f32x4& c, s16x8 a, s16x8 b) {
    asm("v_mfma_f32_16x16x32_bf16 %0, %1, %2, %0" : "+v"(c) : "v"(a), "v"(b));
}
__device__ __forceinline__ void load_lds16(const void* g, void* l) {
    __builtin_amdgcn_global_load_lds(
        (const __attribute__((address_space(1))) uint32_t*)g,
        (__attribute__((address_space(3))) uint32_t*)l, 16, 0, 0);
}

#define SCHED0 __builtin_amdgcn_sched_barrier(0)
#define SBAR do { SCHED0; __builtin_amdgcn_s_barrier(); SCHED0; } while (0)
#define WAIT_VM(N) do { asm volatile("s_waitcnt vmcnt(" #N ")" ::: "memory"); SCHED0; } while (0)

// LDS byte map (128 KiB): buf0.A=0, buf0.B=32768, buf1.A=65536, buf1.B=98304
#define C0 0
#define C1 65536

__global__ __launch_bounds__(512, 2) void k_gemm(
    const unsigned short* __restrict__ Xb,
    const unsigned short* __restrict__ Wb,
    const float* __restrict__ scale_p,
    float* __restrict__ out)
{
    extern __shared__ uint8_t smem[];
    const int tid  = threadIdx.x;
    const int lane = tid & 63;
    const int wid  = tid >> 6;
    const int wr   = wid >> 2;          // 0..1
    const int wc   = wid & 3;           // 0..3

    // XCD-aware bijective swizzle (1024 % 8 == 0)
    const int bid = blockIdx.x;
    const int swz = (bid & 7) * 128 + (bid >> 3);
    const int tileRow = swz >> 5;       // 0..31
    const int tileCol = swz & 31;

    const uint8_t* gA = (const uint8_t*)Xb + (size_t)tileRow * 256 * K2;
    const uint8_t* gB = (const uint8_t*)Wb + (size_t)tileCol * 256 * K2;

    // staging: thread t covers row srow and srow+64 of a 128-row x 64-K half-region.
    // physical LDS slot c of row r holds global col-slot (c ^ (r&7))  (XOR swizzle).
    const int srow = tid >> 3, sslot = tid & 7;
    const size_t srcOff = (size_t)srow * K2 + (size_t)((sslot ^ (srow & 7)) * 16);
    const uint8_t* gAs = gA + srcOff;
    const uint8_t* gBs = gB + srcOff;
    const int dstOff = tid * 16;

    // LDS read bases (byte offsets); frag m adds m*2048 (16 rows * 128B)
    const int rA = wr * 128 + (lane & 15);
    const int rB = wc * 64  + (lane & 15);
    const int h  = lane >> 4;
    const int pA0 = rA * 128 + (((h    ) ^ (rA & 7)) * 16);
    const int pA1 = rA * 128 + (((4 + h) ^ (rA & 7)) * 16);
    const int pB0 = rB * 128 + (((h    ) ^ (rB & 7)) * 16);
    const int pB1 = rB * 128 + (((4 + h) ^ (rB & 7)) * 16);

    s16x8 a[8][2], b[4][2];
    f32x4 acc[8][4];
    #pragma unroll
    for (int m = 0; m < 8; ++m)
        #pragma unroll
        for (int n = 0; n < 4; ++n) acc[m][n] = (f32x4){0.f, 0.f, 0.f, 0.f};

#define LD8(OFF) (*(const s16x8*)(smem + (OFF)))
#define STAGE(LBASE, GP, BOFF) do { \
    load_lds16((GP) + (BOFF),          smem + (LBASE) + dstOff); \
    load_lds16((GP) + (BOFF) + 262144, smem + (LBASE) + 8192 + dstOff); \
    SCHED0; } while (0)

#define RD_A03(AB) do { _Pragma("unroll") for (int m = 0; m < 4; ++m) { \
    a[m][0] = LD8((AB) + pA0 + m * 2048); a[m][1] = LD8((AB) + pA1 + m * 2048); } } while (0)
#define RD_A47(AB) do { _Pragma("unroll") for (int m = 4; m < 8; ++m) { \
    a[m][0] = LD8((AB) + pA0 + m * 2048); a[m][1] = LD8((AB) + pA1 + m * 2048); } } while (0)
#define RD_B01(AB) do { _Pragma("unroll") for (int n = 0; n < 2; ++n) { \
    b[n][0] = LD8((AB) + 32768 + pB0 + n * 2048); b[n][1] = LD8((AB) + 32768 + pB1 + n * 2048); } } while (0)
#define RD_B23(AB) do { _Pragma("unroll") for (int n = 2; n < 4; ++n) { \
    b[n][0] = LD8((AB) + 32768 + pB0 + n * 2048); b[n][1] = LD8((AB) + 32768 + pB1 + n * 2048); } } while (0)

#define MFMA_Q(MLO, NLO) do { \
    __builtin_amdgcn_s_setprio(1); \
    _Pragma("unroll") for (int kk = 0; kk < 2; ++kk) \
        _Pragma("unroll") for (int m = 0; m < 4; ++m) \
            _Pragma("unroll") for (int n = 0; n < 2; ++n) \
                mfma16(acc[(MLO) + m][(NLO) + n], a[(MLO) + m][kk], b[(NLO) + n][kk]); \
    __builtin_amdgcn_s_setprio(0); \
    SCHED0; } while (0)

// One K-tile. CB = current buffer, OB = next-tile buffer; KO2 = byte k-offset of
// tile T+2 (staged into CB); SEN = stage enable, NEN = next-tile-read enable.
#define TILE(CB, OB, KO2, SEN, NEN) do { \
    /* ph1 */ \
    RD_B01(CB); \
    MFMA_Q(0, 0); \
    /* ph2 */ \
    RD_A47(CB); \
    MFMA_Q(0, 2); \
    WAIT_VM(0); SBAR; \
    /* ph3 */ \
    if (NEN) RD_A03(OB); \
    if (SEN) { STAGE((CB) + 32768, gBs, (KO2)); STAGE((CB) + 49152, gBs, 524288 + (KO2)); } \
    MFMA_Q(4, 2); \
    SBAR; \
    /* ph4 */ \
    if (NEN) RD_B23(OB); \
    if (SEN) { STAGE((CB), gAs, (KO2)); STAGE((CB) + 16384, gAs, 524288 + (KO2)); } \
    MFMA_Q(4, 0); \
} while (0)

    // prologue: stage tiles 0 (C0) and 1 (C1); force tile 0, leave tile 1's 8 in
    // flight; preload a03(0), b23(0) (normally read at T-1 ph3/ph4).
    STAGE(C0,         gAs, 0);   STAGE(C0 + 16384, gAs, 524288);
    STAGE(C0 + 32768, gBs, 0);   STAGE(C0 + 49152, gBs, 524288);
    STAGE(C1,         gAs, 128); STAGE(C1 + 16384, gAs, 524288 + 128);
    STAGE(C1 + 32768, gBs, 128); STAGE(C1 + 49152, gBs, 524288 + 128);
    WAIT_VM(8);
    SBAR;
    RD_A03(C0);
    RD_B23(C0);
    SCHED0;

    #pragma unroll 1
    for (int i = 0; i < 15; ++i) {
        const int kb0 = (2 * i + 2) * 128;   // T+2 (staged during even tile)
        const int kb1 = (2 * i + 3) * 128;   // T+3 (staged during odd tile)
        TILE(C0, C1, kb0, 1, 1);
        TILE(C1, C0, kb1, 1, 1);
    }
    // tail: tile 30 (C0; reads tile 31 from C1, no stages), tile 31 (C1, no next)
    TILE(C0, C1, 0, 0, 1);
    TILE(C1, C0, 0, 0, 0);

    // epilogue: C[row][col], col=lane&15, row=(lane>>4)*4+j (verified mapping)
    const float sc = *scale_p;
    const int orow0 = tileRow * 256 + wr * 128 + ((lane >> 4) << 2);
    const int ocol0 = tileCol * 256 + wc * 64 + (lane & 15);
    #pragma unroll
    for (int m = 0; m < 8; ++m)
        #pragma unroll
        for (int n = 0; n < 4; ++n)
            #pragma unroll
            for (int j = 0; j < 4; ++j)
                out[(size_t)(orow0 + m * 16 + j) * N_DIM + (ocol0 + n * 16)] = acc[m][n][j] * sc;

#undef LD8
#undef STAGE
#undef RD_A03
#undef RD_A47
#undef RD_B01
#undef RD_B23
#undef MFMA_Q
#undef TILE
}

// ---------------- launch ----------------
extern "C" void kernel_launch(void* const* d_in, const int* in_sizes, int n_in,
                              void* d_out, int out_size, void* d_ws, size_t ws_size,
                              hipStream_t stream) {
    const float* x = (const float*)d_in[0];
    const float* w = (const float*)d_in[1];
    float* out = (float*)d_out;
    uint8_t* ws = (uint8_t*)d_ws;

    float* part  = (float*)ws;                       // 1024 floats
    float* scale = (float*)(ws + 4096);              // 1 float
    unsigned short* Xb = (unsigned short*)(ws + 8192);
    unsigned short* Wb = (unsigned short*)(ws + 8192 + 33554432ull);

    (void)hipFuncSetAttribute((const void*)k_gemm,
                              hipFuncAttributeMaxDynamicSharedMemorySize, 131072);

    hipLaunchKernelGGL(k_abs_part, dim3(1024), dim3(256), 0, stream, (const float4*)w, part);
    hipLaunchKernelGGL(k_abs_final, dim3(1), dim3(256), 0, stream, part, scale);
    hipLaunchKernelGGL(k_prep, dim3(4096), dim3(256), 0, stream,
                       (const float4*)w, (const float4*)x, scale, (uint2*)Wb, (uint2*)Xb);
    hipLaunchKernelGGL(k_gemm, dim3(1024), dim3(512), 131072, stream, Xb, Wb, scale, out);
}